// Round 4
// baseline (202.470 us; speedup 1.0000x reference)
//
#include <hip/hip_runtime.h>
#include <stdint.h>

#define B_ 2
#define C_ 512
#define G_ 2048
#define H_ 32
#define D_ 128
#define F_ 64
#define N_ (G_ + C_)      // 2560
#define NPAD 4096
#define CHUNK 32          // bottom rows staged per accum iteration
#define NITER (C_ / CHUNK)

// padded LDS slot: one 8B pad per 16 elements; per-write-instruction bank
// pattern becomes 2-way (free) instead of 32-way.
#define PIDX(i) ((i) + ((i) >> 4))

__device__ __forceinline__ unsigned long long shfl64_xor(unsigned long long x,
                                                         int lanex) {
  unsigned int lo = (unsigned int)x, hi = (unsigned int)(x >> 32);
  lo = __shfl_xor(lo, lanex, 64);
  hi = __shfl_xor(hi, lanex, 64);
  return ((unsigned long long)hi << 32) | (unsigned long long)lo;
}

// ---------------------------------------------------------------------------
// Kernel 1: per-(b,h) stable descending argsort of 2560 scores.
// Bitonic sort of 4096 uint64 keys, 512 threads x 8 register-resident elems.
// key = (~orderable(score) << 32) | index  (unique keys -> exact stable sort).
//   j <= 4   : pure register compare-exchange
//   8<=j<=256: __shfl_xor with thread tid^(j/8)  (in-wave, no LDS/barrier)
//   j >= 512 : LDS exchange (write own 8, barrier, read partner's 8) — only
//              6 such phases in the whole network.
// ---------------------------------------------------------------------------
__global__ __launch_bounds__(512) void sort_kernel(
    const float* __restrict__ heap_score,   // (B,G,H)
    const float* __restrict__ score_c,      // (B,C,H)
    float* __restrict__ heap_new,           // (B,G,H)
    int* __restrict__ ws_idx)               // (B*H, 2560)
{
  __shared__ unsigned long long keys[NPAD + (NPAD >> 4)];   // 34 KB
  const int blk = blockIdx.x;               // b*H + h
  const int b = blk >> 5, h = blk & 31;
  const int tid = threadIdx.x;

  unsigned long long v[8];
  #pragma unroll
  for (int l = 0; l < 8; ++l) {
    int r = tid * 8 + l;
    unsigned long long key = 0xFFFFFFFFFFFFFFFFull;   // dummy sinks to end
    if (r < N_) {
      float s = (r < G_) ? heap_score[((size_t)b * G_ + r) * H_ + h]
                         : score_c[((size_t)b * C_ + (r - G_)) * H_ + h];
      unsigned int bits = __float_as_uint(s);
      unsigned int ord = (bits & 0x80000000u) ? ~bits : (bits | 0x80000000u);
      key = ((unsigned long long)(~ord) << 32) | (unsigned int)r;
    }
    v[l] = key;
  }

  auto ce = [&](int x, int y, bool desc) {
    unsigned long long a = v[x], c = v[y];
    if ((a > c) != desc) { v[x] = c; v[y] = a; }
  };

  // ---- build sorted runs of 8 (stages k=2,4,8; i = 8*tid + l) ------------
  {
    const bool t1 = (tid & 1) != 0;         // (i & 8)
    ce(0,1,false); ce(2,3,true);  ce(4,5,false); ce(6,7,true);   // k=2
    ce(0,2,false); ce(1,3,false); ce(4,6,true);  ce(5,7,true);   // k=4 j=2
    ce(0,1,false); ce(2,3,false); ce(4,5,true);  ce(6,7,true);   // k=4 j=1
    ce(0,4,t1); ce(1,5,t1); ce(2,6,t1); ce(3,7,t1);              // k=8 j=4
    ce(0,2,t1); ce(1,3,t1); ce(4,6,t1); ce(5,7,t1);              // k=8 j=2
    ce(0,1,t1); ce(2,3,t1); ce(4,5,t1); ce(6,7,t1);              // k=8 j=1
  }

  // ---- stages k=16..4096 --------------------------------------------------
  for (int k = 16; k <= NPAD; k <<= 1) {
    const bool desc = (((unsigned)tid << 3) & (unsigned)k) != 0;  // (8t & k)

    for (int j = k >> 1; j >= 512; j >>= 1) {         // cross-wave: LDS
      __syncthreads();                                 // protect prior reads
      #pragma unroll
      for (int l = 0; l < 8; ++l) keys[PIDX(tid * 8 + l)] = v[l];
      __syncthreads();
      const int pt = tid ^ (j >> 3);
      const bool up = (tid & (j >> 3)) != 0;
      #pragma unroll
      for (int l = 0; l < 8; ++l) {
        unsigned long long o = keys[PIDX(pt * 8 + l)];
        unsigned long long mn = (v[l] < o) ? v[l] : o;
        unsigned long long mx = (v[l] < o) ? o : v[l];
        v[l] = (up != desc) ? mx : mn;
      }
    }

    #pragma unroll
    for (int j = 256; j >= 8; j >>= 1) {              // in-wave: shuffles
      if (j <= (k >> 1)) {
        const int lanex = j >> 3;                     // 1..32
        const bool up = (tid & lanex) != 0;
        #pragma unroll
        for (int l = 0; l < 8; ++l) {
          unsigned long long o = shfl64_xor(v[l], lanex);
          unsigned long long mn = (v[l] < o) ? v[l] : o;
          unsigned long long mx = (v[l] < o) ? o : v[l];
          v[l] = (up != desc) ? mx : mn;
        }
      }
    }

    ce(0,4,desc); ce(1,5,desc); ce(2,6,desc); ce(3,7,desc);      // j=4
    ce(0,2,desc); ce(1,3,desc); ce(4,6,desc); ce(5,7,desc);      // j=2
    ce(0,1,desc); ce(2,3,desc); ce(4,5,desc); ce(6,7,desc);      // j=1
  }

  // ---- outputs straight from registers -----------------------------------
  if (tid < N_ / 8) {                                  // tid < 320
    int4 lo4 = { (int)(unsigned)v[0], (int)(unsigned)v[1],
                 (int)(unsigned)v[2], (int)(unsigned)v[3] };
    int4 hi4 = { (int)(unsigned)v[4], (int)(unsigned)v[5],
                 (int)(unsigned)v[6], (int)(unsigned)v[7] };
    int4* p = (int4*)(ws_idx + (size_t)blk * N_);
    p[2 * tid] = lo4;
    p[2 * tid + 1] = hi4;
  }
  if (tid < G_ / 8) {                                  // tid < 256
    #pragma unroll
    for (int l = 0; l < 8; ++l) {
      int r = tid * 8 + l;
      unsigned int ord = ~(unsigned int)(v[l] >> 32);
      unsigned int bits = (ord & 0x80000000u) ? (ord & 0x7FFFFFFFu) : ~ord;
      heap_new[((size_t)b * G_ + r) * H_ + h] = __uint_as_float(bits);
    }
  }
}

// ---------------------------------------------------------------------------
// Kernel 2: fused gather (blocks [0,NG)) + bottom-rows accumulation
// (blocks [NG, NG+64)). Accum blocks each own one (b,h): loop 16 chunks of
// 32 rows, stage V/FK in LDS, accumulate 4f x 8d per thread in registers,
// epilogue H_new = H_sum + acc, S_new = S_sum + colsum. Runs concurrently
// with the gather blocks -> fully hidden under the HBM-bound gather.
// ---------------------------------------------------------------------------
#define NK4 ((long long)B_ * G_ * H_ * (D_ / 4))       // 4194304
#define NTOT4 ((long long)B_ * G_ * H_ * (2 * (D_ / 4) + (F_ / 4)))
#define NG ((int)(NTOT4 / 256))                        // 40960 gather blocks

__global__ __launch_bounds__(256) void fused_kernel(
    const float4* __restrict__ K_top,  const float4* __restrict__ k_c,
    const float4* __restrict__ V_top,  const float4* __restrict__ v_c,
    const float4* __restrict__ FK_top, const float4* __restrict__ fk_c,
    float4* __restrict__ K_new, float4* __restrict__ V_new,
    float4* __restrict__ FK_new,
    const float* __restrict__ H_sum, const float* __restrict__ S_sum,
    float* __restrict__ H_new, float* __restrict__ S_new,
    const int* __restrict__ ws_idx)
{
  __shared__ float fk_s[CHUNK][F_];   // 8 KB
  __shared__ float v_s[CHUNK][D_];    // 16 KB
  __shared__ int idx_all[C_];         // 2 KB

  const int tid = threadIdx.x;

  if (blockIdx.x < NG) {
    // ----- gather: one float4 per thread --------------------------------
    long long gid = (long long)blockIdx.x * 256 + tid;
    const float4 *top, *cc;
    float4* d;
    int lg;
    long long g2;
    if (gid < NK4)          { top = K_top;  cc = k_c;  d = K_new;  lg = 5; g2 = gid; }
    else if (gid < 2 * NK4) { top = V_top;  cc = v_c;  d = V_new;  lg = 5; g2 = gid - NK4; }
    else                    { top = FK_top; cc = fk_c; d = FK_new; lg = 4; g2 = gid - 2 * NK4; }

    int row = (int)(g2 >> lg);              // [0, B*G*H)
    int lane = (int)(g2 & ((1 << lg) - 1));
    int b = row >> 16;                      // G*H = 65536
    int g = (row >> 5) & (G_ - 1);
    int h = row & 31;
    int idx = ws_idx[((b << 5) | h) * N_ + g];
    const float4* src;
    if (idx < G_) src = top + (((size_t)(b * G_ + idx) * H_ + h) << lg);
    else          src = cc  + (((size_t)(b * C_ + (idx - G_)) * H_ + h) << lg);
    d[g2] = src[lane];
    return;
  }

  // ----- accumulation: one block per (b,h) ------------------------------
  const int pair = blockIdx.x - NG;         // 0..63
  const int b = pair >> 5, h = pair & 31;
  const int ft = tid >> 4, dt = tid & 15;
  const int f0 = ft * 4, d0 = dt * 8;

  for (int i = tid; i < C_; i += 256)
    idx_all[i] = ws_idx[pair * N_ + G_ + i];

  float acc[4][8];
  #pragma unroll
  for (int i = 0; i < 4; i++)
    #pragma unroll
    for (int j = 0; j < 8; j++) acc[i][j] = 0.f;
  float sacc = 0.f;

  for (int it = 0; it < NITER; ++it) {
    __syncthreads();                        // idx ready / prev compute done
    for (int i = tid; i < CHUNK * 32; i += 256) {      // V rows, 32 f4/row
      int rr = i >> 5, lane = i & 31;
      int idx = idx_all[it * CHUNK + rr];
      const float4* src = (idx < G_)
          ? V_top + (((size_t)(b * G_ + idx) * H_ + h) << 5)
          : v_c  + (((size_t)(b * C_ + (idx - G_)) * H_ + h) << 5);
      ((float4*)v_s)[i] = src[lane];
    }
    for (int i = tid; i < CHUNK * 16; i += 256) {      // FK rows, 16 f4/row
      int rr = i >> 4, lane = i & 15;
      int idx = idx_all[it * CHUNK + rr];
      const float4* src = (idx < G_)
          ? FK_top + (((size_t)(b * G_ + idx) * H_ + h) << 4)
          : fk_c  + (((size_t)(b * C_ + (idx - G_)) * H_ + h) << 4);
      ((float4*)fk_s)[i] = src[lane];
    }
    __syncthreads();

    #pragma unroll 4
    for (int cc = 0; cc < CHUNK; ++cc) {
      float4 fk4 = *(const float4*)&fk_s[cc][f0];
      float4 va = *(const float4*)&v_s[cc][d0];
      float4 vb = *(const float4*)&v_s[cc][d0 + 4];
      float fs[4] = {fk4.x, fk4.y, fk4.z, fk4.w};
      float vs[8] = {va.x, va.y, va.z, va.w, vb.x, vb.y, vb.z, vb.w};
      #pragma unroll
      for (int i = 0; i < 4; i++)
        #pragma unroll
        for (int j = 0; j < 8; j++)
          acc[i][j] = fmaf(fs[i], vs[j], acc[i][j]);
    }
    if (tid < F_) {
      float s = 0.f;
      #pragma unroll 4
      for (int cc = 0; cc < CHUNK; ++cc) s += fk_s[cc][tid];
      sacc += s;
    }
  }

  // ----- epilogue: add prior sums, write outputs ------------------------
  const float* Hs = H_sum + (size_t)pair * F_ * D_;
  float* Hn = H_new + (size_t)pair * F_ * D_;
  #pragma unroll
  for (int i = 0; i < 4; i++) {
    const float4* hs = (const float4*)&Hs[(size_t)(f0 + i) * D_ + d0];
    float4* hn = (float4*)&Hn[(size_t)(f0 + i) * D_ + d0];
    float4 a = hs[0], c = hs[1];
    a.x += acc[i][0]; a.y += acc[i][1]; a.z += acc[i][2]; a.w += acc[i][3];
    c.x += acc[i][4]; c.y += acc[i][5]; c.z += acc[i][6]; c.w += acc[i][7];
    hn[0] = a; hn[1] = c;
  }
  if (tid < F_)
    S_new[(size_t)pair * F_ + tid] = S_sum[(size_t)pair * F_ + tid] + sacc;
}

extern "C" void kernel_launch(void* const* d_in, const int* in_sizes, int n_in,
                              void* d_out, int out_size, void* d_ws, size_t ws_size,
                              hipStream_t stream) {
  const float* heap_score = (const float*)d_in[0];
  const float* K_top  = (const float*)d_in[1];
  const float* V_top  = (const float*)d_in[2];
  const float* FK_top = (const float*)d_in[3];
  const float* H_sum  = (const float*)d_in[4];
  const float* S_sum  = (const float*)d_in[5];
  const float* k_c    = (const float*)d_in[6];
  const float* v_c    = (const float*)d_in[7];
  const float* fk_c   = (const float*)d_in[8];
  const float* score_c = (const float*)d_in[9];

  float* out = (float*)d_out;
  float* heap_new = out;                                        // B*G*H
  float* K_new  = heap_new + (size_t)B_ * G_ * H_;              // B*G*H*D
  float* V_new  = K_new + (size_t)B_ * G_ * H_ * D_;
  float* FK_new = V_new + (size_t)B_ * G_ * H_ * D_;            // B*G*H*F
  float* H_new  = FK_new + (size_t)B_ * G_ * H_ * F_;           // B*H*F*D
  float* S_new  = H_new + (size_t)B_ * H_ * F_ * D_;            // B*H*F

  int* ws_idx = (int*)d_ws;                                     // 655360 B

  sort_kernel<<<B_ * H_, 512, 0, stream>>>(heap_score, score_c, heap_new, ws_idx);

  fused_kernel<<<NG + B_ * H_, 256, 0, stream>>>(
      (const float4*)K_top, (const float4*)k_c,
      (const float4*)V_top, (const float4*)v_c,
      (const float4*)FK_top, (const float4*)fk_c,
      (float4*)K_new, (float4*)V_new, (float4*)FK_new,
      H_sum, S_sum, H_new, S_new, ws_idx);
}

// Round 6
// 117.609 us; speedup vs baseline: 1.7215x; 1.7215x over previous
//
#include <hip/hip_runtime.h>
#include <stdint.h>

#define B_ 2
#define C_ 512
#define G_ 2048
#define H_ 32
#define D_ 128
#define F_ 64
#define N_ (G_ + C_)      // 2560
#define NPAD 4096
#define CHUNKS 8
#define CHUNK 64          // bottom rows per accum workgroup

// padded LDS slot for the sort's cross-wave exchanges
#define PIDX(i) ((i) + ((i) >> 4))

// native vector type for __builtin_nontemporal_* (HIP float4 is a class and
// is rejected by the builtin; this alias is layout-identical)
typedef float nt_f4 __attribute__((ext_vector_type(4)));

__device__ __forceinline__ unsigned long long shfl64_xor(unsigned long long x,
                                                         int lanex) {
  unsigned int lo = (unsigned int)x, hi = (unsigned int)(x >> 32);
  lo = __shfl_xor(lo, lanex, 64);
  hi = __shfl_xor(hi, lanex, 64);
  return ((unsigned long long)hi << 32) | (unsigned long long)lo;
}

// ---------------------------------------------------------------------------
// Kernel 1: per-(b,h) stable descending argsort of 2560 scores.
// Bitonic sort of 4096 uint64 keys, 512 threads x 8 register-resident elems.
// key = (~orderable(score) << 32) | index  (unique keys -> exact stable sort).
//   j <= 4   : register compare-exchange
//   8<=j<=256: __shfl_xor with thread tid^(j/8)  (in-wave, no LDS/barrier)
//   j >= 512 : LDS exchange (6 phases total in the whole network)
// Verified bit-exact in round 4 (absmax 0.0).
// ---------------------------------------------------------------------------
__global__ __launch_bounds__(512) void sort_kernel(
    const float* __restrict__ heap_score,   // (B,G,H)
    const float* __restrict__ score_c,      // (B,C,H)
    float* __restrict__ heap_new,           // (B,G,H)
    int* __restrict__ ws_idx)               // (B*H, 2560)
{
  __shared__ unsigned long long keys[NPAD + (NPAD >> 4)];   // 34 KB
  const int blk = blockIdx.x;               // b*H + h
  const int b = blk >> 5, h = blk & 31;
  const int tid = threadIdx.x;

  unsigned long long v[8];
  #pragma unroll
  for (int l = 0; l < 8; ++l) {
    int r = tid * 8 + l;
    unsigned long long key = 0xFFFFFFFFFFFFFFFFull;   // dummy sinks to end
    if (r < N_) {
      float s = (r < G_) ? heap_score[((size_t)b * G_ + r) * H_ + h]
                         : score_c[((size_t)b * C_ + (r - G_)) * H_ + h];
      unsigned int bits = __float_as_uint(s);
      unsigned int ord = (bits & 0x80000000u) ? ~bits : (bits | 0x80000000u);
      key = ((unsigned long long)(~ord) << 32) | (unsigned int)r;
    }
    v[l] = key;
  }

  auto ce = [&](int x, int y, bool desc) {
    unsigned long long a = v[x], c = v[y];
    if ((a > c) != desc) { v[x] = c; v[y] = a; }
  };

  // ---- build sorted runs of 8 (stages k=2,4,8; i = 8*tid + l) ------------
  {
    const bool t1 = (tid & 1) != 0;         // (i & 8)
    ce(0,1,false); ce(2,3,true);  ce(4,5,false); ce(6,7,true);   // k=2
    ce(0,2,false); ce(1,3,false); ce(4,6,true);  ce(5,7,true);   // k=4 j=2
    ce(0,1,false); ce(2,3,false); ce(4,5,true);  ce(6,7,true);   // k=4 j=1
    ce(0,4,t1); ce(1,5,t1); ce(2,6,t1); ce(3,7,t1);              // k=8 j=4
    ce(0,2,t1); ce(1,3,t1); ce(4,6,t1); ce(5,7,t1);              // k=8 j=2
    ce(0,1,t1); ce(2,3,t1); ce(4,5,t1); ce(6,7,t1);              // k=8 j=1
  }

  // ---- stages k=16..4096 --------------------------------------------------
  for (int k = 16; k <= NPAD; k <<= 1) {
    const bool desc = (((unsigned)tid << 3) & (unsigned)k) != 0;  // (8t & k)

    for (int j = k >> 1; j >= 512; j >>= 1) {         // cross-wave: LDS
      __syncthreads();                                 // protect prior reads
      #pragma unroll
      for (int l = 0; l < 8; ++l) keys[PIDX(tid * 8 + l)] = v[l];
      __syncthreads();
      const int pt = tid ^ (j >> 3);
      const bool up = (tid & (j >> 3)) != 0;
      #pragma unroll
      for (int l = 0; l < 8; ++l) {
        unsigned long long o = keys[PIDX(pt * 8 + l)];
        unsigned long long mn = (v[l] < o) ? v[l] : o;
        unsigned long long mx = (v[l] < o) ? o : v[l];
        v[l] = (up != desc) ? mx : mn;
      }
    }

    #pragma unroll
    for (int j = 256; j >= 8; j >>= 1) {              // in-wave: shuffles
      if (j <= (k >> 1)) {
        const int lanex = j >> 3;                     // 1..32
        const bool up = (tid & lanex) != 0;
        #pragma unroll
        for (int l = 0; l < 8; ++l) {
          unsigned long long o = shfl64_xor(v[l], lanex);
          unsigned long long mn = (v[l] < o) ? v[l] : o;
          unsigned long long mx = (v[l] < o) ? o : v[l];
          v[l] = (up != desc) ? mx : mn;
        }
      }
    }

    ce(0,4,desc); ce(1,5,desc); ce(2,6,desc); ce(3,7,desc);      // j=4
    ce(0,2,desc); ce(1,3,desc); ce(4,6,desc); ce(5,7,desc);      // j=2
    ce(0,1,desc); ce(2,3,desc); ce(4,5,desc); ce(6,7,desc);      // j=1
  }

  // ---- outputs straight from registers -----------------------------------
  if (tid < N_ / 8) {                                  // tid < 320
    int4 lo4 = { (int)(unsigned)v[0], (int)(unsigned)v[1],
                 (int)(unsigned)v[2], (int)(unsigned)v[3] };
    int4 hi4 = { (int)(unsigned)v[4], (int)(unsigned)v[5],
                 (int)(unsigned)v[6], (int)(unsigned)v[7] };
    int4* p = (int4*)(ws_idx + (size_t)blk * N_);
    p[2 * tid] = lo4;
    p[2 * tid + 1] = hi4;
  }
  if (tid < G_ / 8) {                                  // tid < 256
    #pragma unroll
    for (int l = 0; l < 8; ++l) {
      int r = tid * 8 + l;
      unsigned int ord = ~(unsigned int)(v[l] >> 32);
      unsigned int bits = (ord & 0x80000000u) ? (ord & 0x7FFFFFFFu) : ~ord;
      heap_new[((size_t)b * G_ + r) * H_ + h] = __uint_as_float(bits);
    }
  }
}

// ---------------------------------------------------------------------------
// Kernel 2: fused row gather for K, V, FK. ILP-4: four independent
// idx->addr->load chains per thread, all loads issued before any store.
// No LDS, low VGPR -> max occupancy. Data is read-once / write-once ->
// non-temporal to keep L2 for the shared ws_idx broadcasts.
// ---------------------------------------------------------------------------
#define NK4 ((long long)B_ * G_ * H_ * (D_ / 4))       // 4194304
#define NTOT4 ((long long)B_ * G_ * H_ * (2 * (D_ / 4) + (F_ / 4)))  // 10485760
#define QUARTER (NTOT4 / 4)                            // 2621440 (mult of 256)

__device__ __forceinline__ void gather_one(
    long long gid,
    const float4* __restrict__ K_top,  const float4* __restrict__ k_c,
    const float4* __restrict__ V_top,  const float4* __restrict__ v_c,
    const float4* __restrict__ FK_top, const float4* __restrict__ fk_c,
    float4* __restrict__ K_new, float4* __restrict__ V_new,
    float4* __restrict__ FK_new,
    const int* __restrict__ ws_idx,
    const nt_f4** src, nt_f4** dst)
{
  const float4 *top, *cc;
  float4* d;
  int lg;
  long long g2;
  if (gid < NK4)          { top = K_top;  cc = k_c;  d = K_new;  lg = 5; g2 = gid; }
  else if (gid < 2 * NK4) { top = V_top;  cc = v_c;  d = V_new;  lg = 5; g2 = gid - NK4; }
  else                    { top = FK_top; cc = fk_c; d = FK_new; lg = 4; g2 = gid - 2 * NK4; }

  int row = (int)(g2 >> lg);                // [0, B*G*H)
  int lane = (int)(g2 & ((1 << lg) - 1));
  int b = row >> 16;                        // G*H = 65536
  int g = (row >> 5) & (G_ - 1);
  int h = row & 31;
  int idx = ws_idx[((b << 5) | h) * N_ + g];
  const float4* s;
  if (idx < G_) s = top + (((size_t)(b * G_ + idx) * H_ + h) << lg) + lane;
  else          s = cc  + (((size_t)(b * C_ + (idx - G_)) * H_ + h) << lg) + lane;
  *src = (const nt_f4*)s;
  *dst = (nt_f4*)(d + g2);
}

__global__ __launch_bounds__(256) void gather_all(
    const float4* __restrict__ K_top,  const float4* __restrict__ k_c,
    const float4* __restrict__ V_top,  const float4* __restrict__ v_c,
    const float4* __restrict__ FK_top, const float4* __restrict__ fk_c,
    float4* __restrict__ K_new, float4* __restrict__ V_new,
    float4* __restrict__ FK_new,
    const int* __restrict__ ws_idx)
{
  long long gid = (long long)blockIdx.x * 256 + threadIdx.x;

  const nt_f4 *s0, *s1, *s2, *s3;
  nt_f4 *d0, *d1, *d2, *d3;
  gather_one(gid,               K_top, k_c, V_top, v_c, FK_top, fk_c,
             K_new, V_new, FK_new, ws_idx, &s0, &d0);
  gather_one(gid + QUARTER,     K_top, k_c, V_top, v_c, FK_top, fk_c,
             K_new, V_new, FK_new, ws_idx, &s1, &d1);
  gather_one(gid + 2 * QUARTER, K_top, k_c, V_top, v_c, FK_top, fk_c,
             K_new, V_new, FK_new, ws_idx, &s2, &d2);
  gather_one(gid + 3 * QUARTER, K_top, k_c, V_top, v_c, FK_top, fk_c,
             K_new, V_new, FK_new, ws_idx, &s3, &d3);
  nt_f4 a = __builtin_nontemporal_load(s0);
  nt_f4 b = __builtin_nontemporal_load(s1);
  nt_f4 c = __builtin_nontemporal_load(s2);
  nt_f4 e = __builtin_nontemporal_load(s3);
  __builtin_nontemporal_store(a, d0);
  __builtin_nontemporal_store(b, d1);
  __builtin_nontemporal_store(c, d2);
  __builtin_nontemporal_store(e, d3);
}

// ---------------------------------------------------------------------------
// Kernel 3: per-(b,h) chunk of 64 bottom rows: stage FK (64x64) and V (64x128)
// in LDS, each thread accumulates a 4f x 8d tile over 64 c. Epilogue either
// stores partials to ws (reduced later) or atomic-adds into pre-init output.
// ---------------------------------------------------------------------------
template <bool USE_ATOMIC>
__global__ __launch_bounds__(256) void accum_kernel(
    const float* __restrict__ FK_top, const float* __restrict__ fk_c,
    const float* __restrict__ V_top,  const float* __restrict__ v_c,
    const int* __restrict__ ws_idx,
    float* __restrict__ H_out,        // atomic: H_new (pre-init); else wsH
    float* __restrict__ S_out)        // atomic: S_new (pre-init); else wsS
{
  __shared__ float fk_s[CHUNK][F_];   // 16 KB
  __shared__ float v_s[CHUNK][D_];    // 32 KB
  __shared__ int idx_s[CHUNK];

  const int blk = blockIdx.x;
  const int pair = blk >> 3;          // b*H + h
  const int chunk = blk & 7;
  const int b = pair >> 5, h = pair & 31;
  const int tid = threadIdx.x;

  if (tid < CHUNK) idx_s[tid] = ws_idx[pair * N_ + G_ + chunk * CHUNK + tid];
  __syncthreads();

  for (int i = tid; i < CHUNK * 32; i += 256) {       // V rows, 32 f4/row
    int rr = i >> 5, lane = i & 31;
    int idx = idx_s[rr];
    const float4* src = (idx < G_)
        ? (const float4*)V_top + (((size_t)(b * G_ + idx) * H_ + h) << 5)
        : (const float4*)v_c  + (((size_t)(b * C_ + (idx - G_)) * H_ + h) << 5);
    ((float4*)v_s)[i] = src[lane];
  }
  for (int i = tid; i < CHUNK * 16; i += 256) {       // FK rows, 16 f4/row
    int rr = i >> 4, lane = i & 15;
    int idx = idx_s[rr];
    const float4* src = (idx < G_)
        ? (const float4*)FK_top + (((size_t)(b * G_ + idx) * H_ + h) << 4)
        : (const float4*)fk_c  + (((size_t)(b * C_ + (idx - G_)) * H_ + h) << 4);
    ((float4*)fk_s)[i] = src[lane];
  }
  __syncthreads();

  const int ft = tid >> 4, dt = tid & 15;
  const int f0 = ft * 4, d0 = dt * 8;
  float acc[4][8];
  #pragma unroll
  for (int i = 0; i < 4; i++)
    #pragma unroll
    for (int j = 0; j < 8; j++) acc[i][j] = 0.f;

  for (int cc = 0; cc < CHUNK; ++cc) {
    float4 fk4 = *(const float4*)&fk_s[cc][f0];
    float4 va = *(const float4*)&v_s[cc][d0];
    float4 vb = *(const float4*)&v_s[cc][d0 + 4];
    float fs[4] = {fk4.x, fk4.y, fk4.z, fk4.w};
    float vs[8] = {va.x, va.y, va.z, va.w, vb.x, vb.y, vb.z, vb.w};
    #pragma unroll
    for (int i = 0; i < 4; i++)
      #pragma unroll
      for (int j = 0; j < 8; j++)
        acc[i][j] = fmaf(fs[i], vs[j], acc[i][j]);
  }

  if (USE_ATOMIC) {
    float* Hbase = H_out + ((size_t)pair * F_) * D_;
    #pragma unroll
    for (int i = 0; i < 4; i++)
      #pragma unroll
      for (int j = 0; j < 8; j++)
        atomicAdd(&Hbase[(size_t)(f0 + i) * D_ + d0 + j], acc[i][j]);
    if (tid < F_) {
      float s = 0.f;
      for (int cc = 0; cc < CHUNK; ++cc) s += fk_s[cc][tid];
      atomicAdd(&S_out[(size_t)pair * F_ + tid], s);
    }
  } else {
    float* Hbase = H_out + ((size_t)blk * F_) * D_;   // per-chunk partial
    #pragma unroll
    for (int i = 0; i < 4; i++) {
      float4 lo = {acc[i][0], acc[i][1], acc[i][2], acc[i][3]};
      float4 hi = {acc[i][4], acc[i][5], acc[i][6], acc[i][7]};
      float4* p = (float4*)&Hbase[(size_t)(f0 + i) * D_ + d0];
      p[0] = lo; p[1] = hi;
    }
    if (tid < F_) {
      float s = 0.f;
      for (int cc = 0; cc < CHUNK; ++cc) s += fk_s[cc][tid];
      S_out[(size_t)blk * F_ + tid] = s;
    }
  }
}

// ---------------------------------------------------------------------------
// Kernel 4: reduce 8 chunk partials + H_sum/S_sum into outputs (f4 granular).
// ---------------------------------------------------------------------------
__global__ __launch_bounds__(256) void reduce_kernel(
    const float4* __restrict__ Hsum4, const float4* __restrict__ Ssum4,
    const float4* __restrict__ wsH4,  const float4* __restrict__ wsS4,
    float4* __restrict__ Hnew4,       float4* __restrict__ Snew4)
{
  const int NH4 = B_ * H_ * F_ * D_ / 4;    // 131072
  int gid = blockIdx.x * 256 + threadIdx.x;
  if (gid < NH4) {
    int p = gid >> 11;                      // 2048 f4 per (b,h)
    int e = gid & 2047;
    float4 acc = Hsum4[gid];
    #pragma unroll
    for (int c = 0; c < CHUNKS; ++c) {
      float4 v = wsH4[(((size_t)(p * CHUNKS + c)) << 11) | e];
      acc.x += v.x; acc.y += v.y; acc.z += v.z; acc.w += v.w;
    }
    Hnew4[gid] = acc;
  } else {
    int q = gid - NH4;                      // [0, 1024)
    if (q < B_ * H_ * F_ / 4) {
      int p = q >> 4, fl = q & 15;          // 16 f4 per (b,h)
      float4 acc = Ssum4[q];
      #pragma unroll
      for (int c = 0; c < CHUNKS; ++c) {
        float4 v = wsS4[((p * CHUNKS + c) << 4) | fl];
        acc.x += v.x; acc.y += v.y; acc.z += v.z; acc.w += v.w;
      }
      Snew4[q] = acc;
    }
  }
}

extern "C" void kernel_launch(void* const* d_in, const int* in_sizes, int n_in,
                              void* d_out, int out_size, void* d_ws, size_t ws_size,
                              hipStream_t stream) {
  const float* heap_score = (const float*)d_in[0];
  const float* K_top  = (const float*)d_in[1];
  const float* V_top  = (const float*)d_in[2];
  const float* FK_top = (const float*)d_in[3];
  const float* H_sum  = (const float*)d_in[4];
  const float* S_sum  = (const float*)d_in[5];
  const float* k_c    = (const float*)d_in[6];
  const float* v_c    = (const float*)d_in[7];
  const float* fk_c   = (const float*)d_in[8];
  const float* score_c = (const float*)d_in[9];

  float* out = (float*)d_out;
  float* heap_new = out;                                        // B*G*H
  float* K_new  = heap_new + (size_t)B_ * G_ * H_;              // B*G*H*D
  float* V_new  = K_new + (size_t)B_ * G_ * H_ * D_;
  float* FK_new = V_new + (size_t)B_ * G_ * H_ * D_;            // B*G*H*F
  float* H_new  = FK_new + (size_t)B_ * G_ * H_ * F_;           // B*H*F*D
  float* S_new  = H_new + (size_t)B_ * H_ * F_ * D_;            // B*H*F

  // workspace layout
  int* ws_idx = (int*)d_ws;                                     // 655360 B
  const size_t idx_bytes = (size_t)B_ * H_ * N_ * sizeof(int);
  float* wsH = (float*)((char*)d_ws + idx_bytes);               // 512*8192 f
  float* wsS = wsH + (size_t)B_ * H_ * CHUNKS * F_ * D_;        // 512*64 f
  const size_t ws_needed = idx_bytes
      + (size_t)B_ * H_ * CHUNKS * F_ * D_ * sizeof(float)
      + (size_t)B_ * H_ * CHUNKS * F_ * sizeof(float);

  sort_kernel<<<B_ * H_, 512, 0, stream>>>(heap_score, score_c, heap_new, ws_idx);

  if (ws_size >= ws_needed) {
    accum_kernel<false><<<B_ * H_ * CHUNKS, 256, 0, stream>>>(
        FK_top, fk_c, V_top, v_c, ws_idx, wsH, wsS);
  } else {
    (void)hipMemcpyAsync(H_new, H_sum, sizeof(float) * (size_t)B_ * H_ * F_ * D_,
                         hipMemcpyDeviceToDevice, stream);
    (void)hipMemcpyAsync(S_new, S_sum, sizeof(float) * (size_t)B_ * H_ * F_,
                         hipMemcpyDeviceToDevice, stream);
    accum_kernel<true><<<B_ * H_ * CHUNKS, 256, 0, stream>>>(
        FK_top, fk_c, V_top, v_c, ws_idx, H_new, S_new);
  }

  gather_all<<<(int)(QUARTER / 256), 256, 0, stream>>>(
      (const float4*)K_top, (const float4*)k_c,
      (const float4*)V_top, (const float4*)v_c,
      (const float4*)FK_top, (const float4*)fk_c,
      (float4*)K_new, (float4*)V_new, (float4*)FK_new, ws_idx);

  if (ws_size >= ws_needed) {
    const int ntot4 = B_ * H_ * F_ * D_ / 4 + B_ * H_ * F_ / 4; // 132096
    reduce_kernel<<<(ntot4 + 255) / 256, 256, 0, stream>>>(
        (const float4*)H_sum, (const float4*)S_sum,
        (const float4*)wsH, (const float4*)wsS,
        (float4*)H_new, (float4*)S_new);
  }
}

// Round 7
// 107.609 us; speedup vs baseline: 1.8815x; 1.0929x over previous
//
#include <hip/hip_runtime.h>
#include <stdint.h>

#define B_ 2
#define C_ 512
#define G_ 2048
#define H_ 32
#define D_ 128
#define F_ 64
#define N_ (G_ + C_)      // 2560
#define NPAD 4096

// padded LDS slot for the sort's cross-wave exchanges
#define PIDX(i) ((i) + ((i) >> 4))

// native vector type for __builtin_nontemporal_* (HIP float4 is a class and
// is rejected by the builtin; this alias is layout-identical)
typedef float nt_f4 __attribute__((ext_vector_type(4)));

__device__ __forceinline__ unsigned long long shfl64_xor(unsigned long long x,
                                                         int lanex) {
  unsigned int lo = (unsigned int)x, hi = (unsigned int)(x >> 32);
  lo = __shfl_xor(lo, lanex, 64);
  hi = __shfl_xor(hi, lanex, 64);
  return ((unsigned long long)hi << 32) | (unsigned long long)lo;
}

// ---------------------------------------------------------------------------
// Kernel 1: per-(b,h) stable descending argsort of 2560 scores.
// Bitonic sort of 4096 uint64 keys, 512 threads x 8 register-resident elems.
// key = (~orderable(score) << 32) | index  (unique keys -> exact stable sort).
// Verified bit-exact (round 4: absmax 0.0 on heap path).
// ---------------------------------------------------------------------------
__global__ __launch_bounds__(512) void sort_kernel(
    const float* __restrict__ heap_score,   // (B,G,H)
    const float* __restrict__ score_c,      // (B,C,H)
    float* __restrict__ heap_new,           // (B,G,H)
    int* __restrict__ ws_idx)               // (B*H, 2560)
{
  __shared__ unsigned long long keys[NPAD + (NPAD >> 4)];   // 34 KB
  const int blk = blockIdx.x;               // b*H + h
  const int b = blk >> 5, h = blk & 31;
  const int tid = threadIdx.x;

  unsigned long long v[8];
  #pragma unroll
  for (int l = 0; l < 8; ++l) {
    int r = tid * 8 + l;
    unsigned long long key = 0xFFFFFFFFFFFFFFFFull;   // dummy sinks to end
    if (r < N_) {
      float s = (r < G_) ? heap_score[((size_t)b * G_ + r) * H_ + h]
                         : score_c[((size_t)b * C_ + (r - G_)) * H_ + h];
      unsigned int bits = __float_as_uint(s);
      unsigned int ord = (bits & 0x80000000u) ? ~bits : (bits | 0x80000000u);
      key = ((unsigned long long)(~ord) << 32) | (unsigned int)r;
    }
    v[l] = key;
  }

  auto ce = [&](int x, int y, bool desc) {
    unsigned long long a = v[x], c = v[y];
    if ((a > c) != desc) { v[x] = c; v[y] = a; }
  };

  // ---- build sorted runs of 8 (stages k=2,4,8; i = 8*tid + l) ------------
  {
    const bool t1 = (tid & 1) != 0;         // (i & 8)
    ce(0,1,false); ce(2,3,true);  ce(4,5,false); ce(6,7,true);   // k=2
    ce(0,2,false); ce(1,3,false); ce(4,6,true);  ce(5,7,true);   // k=4 j=2
    ce(0,1,false); ce(2,3,false); ce(4,5,true);  ce(6,7,true);   // k=4 j=1
    ce(0,4,t1); ce(1,5,t1); ce(2,6,t1); ce(3,7,t1);              // k=8 j=4
    ce(0,2,t1); ce(1,3,t1); ce(4,6,t1); ce(5,7,t1);              // k=8 j=2
    ce(0,1,t1); ce(2,3,t1); ce(4,5,t1); ce(6,7,t1);              // k=8 j=1
  }

  // ---- stages k=16..4096 --------------------------------------------------
  for (int k = 16; k <= NPAD; k <<= 1) {
    const bool desc = (((unsigned)tid << 3) & (unsigned)k) != 0;  // (8t & k)

    for (int j = k >> 1; j >= 512; j >>= 1) {         // cross-wave: LDS
      __syncthreads();                                 // protect prior reads
      #pragma unroll
      for (int l = 0; l < 8; ++l) keys[PIDX(tid * 8 + l)] = v[l];
      __syncthreads();
      const int pt = tid ^ (j >> 3);
      const bool up = (tid & (j >> 3)) != 0;
      #pragma unroll
      for (int l = 0; l < 8; ++l) {
        unsigned long long o = keys[PIDX(pt * 8 + l)];
        unsigned long long mn = (v[l] < o) ? v[l] : o;
        unsigned long long mx = (v[l] < o) ? o : v[l];
        v[l] = (up != desc) ? mx : mn;
      }
    }

    #pragma unroll
    for (int j = 256; j >= 8; j >>= 1) {              // in-wave: shuffles
      if (j <= (k >> 1)) {
        const int lanex = j >> 3;                     // 1..32
        const bool up = (tid & lanex) != 0;
        #pragma unroll
        for (int l = 0; l < 8; ++l) {
          unsigned long long o = shfl64_xor(v[l], lanex);
          unsigned long long mn = (v[l] < o) ? v[l] : o;
          unsigned long long mx = (v[l] < o) ? o : v[l];
          v[l] = (up != desc) ? mx : mn;
        }
      }
    }

    ce(0,4,desc); ce(1,5,desc); ce(2,6,desc); ce(3,7,desc);      // j=4
    ce(0,2,desc); ce(1,3,desc); ce(4,6,desc); ce(5,7,desc);      // j=2
    ce(0,1,desc); ce(2,3,desc); ce(4,5,desc); ce(6,7,desc);      // j=1
  }

  // ---- outputs straight from registers -----------------------------------
  if (tid < N_ / 8) {                                  // tid < 320
    int4 lo4 = { (int)(unsigned)v[0], (int)(unsigned)v[1],
                 (int)(unsigned)v[2], (int)(unsigned)v[3] };
    int4 hi4 = { (int)(unsigned)v[4], (int)(unsigned)v[5],
                 (int)(unsigned)v[6], (int)(unsigned)v[7] };
    int4* p = (int4*)(ws_idx + (size_t)blk * N_);
    p[2 * tid] = lo4;
    p[2 * tid + 1] = hi4;
  }
  if (tid < G_ / 8) {                                  // tid < 256
    #pragma unroll
    for (int l = 0; l < 8; ++l) {
      int r = tid * 8 + l;
      unsigned int ord = ~(unsigned int)(v[l] >> 32);
      unsigned int bits = (ord & 0x80000000u) ? (ord & 0x7FFFFFFFu) : ~ord;
      heap_new[((size_t)b * G_ + r) * H_ + h] = __uint_as_float(bits);
    }
  }
}

// ---------------------------------------------------------------------------
// Kernel 2: fused gather + accumulation.
//  blocks [0, ABLOCKS):       accum — 2 blocks per (b,h) (one per d-half).
//    Each loops all 512 bottom rows in 32 chunks of 16, staging FK (16x64)
//    and its V half (16x64) in 10 KB LDS, acc[4][4] in registers, epilogue
//    H_new = H_sum + acc directly (no partials / reduce / atomics).
//    Dispatched FIRST; FMA hides under the memory-bound gather blocks.
//  blocks [ABLOCKS, +NG):     gather — ILP-4 non-temporal row gather
//    (identical to the round-6 gather_all).
// ---------------------------------------------------------------------------
#define NK4 ((long long)B_ * G_ * H_ * (D_ / 4))       // 4194304
#define NTOT4 ((long long)B_ * G_ * H_ * (2 * (D_ / 4) + (F_ / 4)))  // 10485760
#define QUARTER (NTOT4 / 4)                            // 2621440 (mult of 256)
#define NG ((int)(QUARTER / 256))                      // 10240 gather blocks
#define ABLOCKS (2 * B_ * H_)                          // 128 accum blocks
#define ACHUNK 16
#define AITER (C_ / ACHUNK)                            // 32

__device__ __forceinline__ void gather_one(
    long long gid,
    const float4* __restrict__ K_top,  const float4* __restrict__ k_c,
    const float4* __restrict__ V_top,  const float4* __restrict__ v_c,
    const float4* __restrict__ FK_top, const float4* __restrict__ fk_c,
    float4* __restrict__ K_new, float4* __restrict__ V_new,
    float4* __restrict__ FK_new,
    const int* __restrict__ ws_idx,
    const nt_f4** src, nt_f4** dst)
{
  const float4 *top, *cc;
  float4* d;
  int lg;
  long long g2;
  if (gid < NK4)          { top = K_top;  cc = k_c;  d = K_new;  lg = 5; g2 = gid; }
  else if (gid < 2 * NK4) { top = V_top;  cc = v_c;  d = V_new;  lg = 5; g2 = gid - NK4; }
  else                    { top = FK_top; cc = fk_c; d = FK_new; lg = 4; g2 = gid - 2 * NK4; }

  int row = (int)(g2 >> lg);                // [0, B*G*H)
  int lane = (int)(g2 & ((1 << lg) - 1));
  int b = row >> 16;                        // G*H = 65536
  int g = (row >> 5) & (G_ - 1);
  int h = row & 31;
  int idx = ws_idx[((b << 5) | h) * N_ + g];
  const float4* s;
  if (idx < G_) s = top + (((size_t)(b * G_ + idx) * H_ + h) << lg) + lane;
  else          s = cc  + (((size_t)(b * C_ + (idx - G_)) * H_ + h) << lg) + lane;
  *src = (const nt_f4*)s;
  *dst = (nt_f4*)(d + g2);
}

__global__ __launch_bounds__(256) void fused_kernel(
    const float4* __restrict__ K_top,  const float4* __restrict__ k_c,
    const float4* __restrict__ V_top,  const float4* __restrict__ v_c,
    const float4* __restrict__ FK_top, const float4* __restrict__ fk_c,
    float4* __restrict__ K_new, float4* __restrict__ V_new,
    float4* __restrict__ FK_new,
    const float* __restrict__ H_sum, const float* __restrict__ S_sum,
    float* __restrict__ H_new, float* __restrict__ S_new,
    const int* __restrict__ ws_idx)
{
  __shared__ float fk_s[ACHUNK][F_];        // 4 KB
  __shared__ float v_s[ACHUNK][D_ / 2];     // 4 KB
  __shared__ int idx_all[C_];               // 2 KB

  const int tid = threadIdx.x;

  if (blockIdx.x >= ABLOCKS) {
    // ----- gather: ILP-4, non-temporal ----------------------------------
    long long gid = (long long)(blockIdx.x - ABLOCKS) * 256 + tid;

    const nt_f4 *s0, *s1, *s2, *s3;
    nt_f4 *d0, *d1, *d2, *d3;
    gather_one(gid,               K_top, k_c, V_top, v_c, FK_top, fk_c,
               K_new, V_new, FK_new, ws_idx, &s0, &d0);
    gather_one(gid + QUARTER,     K_top, k_c, V_top, v_c, FK_top, fk_c,
               K_new, V_new, FK_new, ws_idx, &s1, &d1);
    gather_one(gid + 2 * QUARTER, K_top, k_c, V_top, v_c, FK_top, fk_c,
               K_new, V_new, FK_new, ws_idx, &s2, &d2);
    gather_one(gid + 3 * QUARTER, K_top, k_c, V_top, v_c, FK_top, fk_c,
               K_new, V_new, FK_new, ws_idx, &s3, &d3);
    nt_f4 a = __builtin_nontemporal_load(s0);
    nt_f4 b = __builtin_nontemporal_load(s1);
    nt_f4 c = __builtin_nontemporal_load(s2);
    nt_f4 e = __builtin_nontemporal_load(s3);
    __builtin_nontemporal_store(a, d0);
    __builtin_nontemporal_store(b, d1);
    __builtin_nontemporal_store(c, d2);
    __builtin_nontemporal_store(e, d3);
    return;
  }

  // ----- accum: one block per (b,h) x d-half ----------------------------
  const int pair = blockIdx.x >> 1;         // 0..63
  const int dhalf = blockIdx.x & 1;
  const int b = pair >> 5, h = pair & 31;

  for (int i = tid; i < C_; i += 256)
    idx_all[i] = ws_idx[pair * N_ + G_ + i];

  const int f0 = (tid >> 4) * 4;            // 0..60 (global f)
  const int d0 = (tid & 15) * 4;            // 0..60 (within half)
  float acc[4][4];
  #pragma unroll
  for (int i = 0; i < 4; i++)
    #pragma unroll
    for (int j = 0; j < 4; j++) acc[i][j] = 0.f;
  float sacc = 0.f;

  const int rr = tid >> 4, lane = tid & 15; // staging role: row, f4-slot

  for (int it = 0; it < AITER; ++it) {
    __syncthreads();                        // idx ready / prev compute done
    int idx = idx_all[it * ACHUNK + rr];
    {                                       // V half: 256 f4, 1 per thread
      const float4* src = (idx < G_)
          ? V_top + (((size_t)(b * G_ + idx) * H_ + h) << 5)
          : v_c  + (((size_t)(b * C_ + (idx - G_)) * H_ + h) << 5);
      ((float4*)v_s)[tid] = src[dhalf * 16 + lane];
    }
    {                                       // FK: 256 f4, 1 per thread
      const float4* src = (idx < G_)
          ? FK_top + (((size_t)(b * G_ + idx) * H_ + h) << 4)
          : fk_c  + (((size_t)(b * C_ + (idx - G_)) * H_ + h) << 4);
      ((float4*)fk_s)[tid] = src[lane];
    }
    __syncthreads();

    #pragma unroll 4
    for (int cc = 0; cc < ACHUNK; ++cc) {
      float4 fk4 = *(const float4*)&fk_s[cc][f0];
      float4 vv = *(const float4*)&v_s[cc][d0];
      float fs[4] = {fk4.x, fk4.y, fk4.z, fk4.w};
      float vs[4] = {vv.x, vv.y, vv.z, vv.w};
      #pragma unroll
      for (int i = 0; i < 4; i++)
        #pragma unroll
        for (int j = 0; j < 4; j++)
          acc[i][j] = fmaf(fs[i], vs[j], acc[i][j]);
    }
    if (dhalf == 0 && tid < F_) {
      float s = 0.f;
      #pragma unroll
      for (int cc = 0; cc < ACHUNK; ++cc) s += fk_s[cc][tid];
      sacc += s;
    }
  }

  // ----- epilogue: H_new = H_sum + acc, S_new = S_sum + sacc ------------
  const float* Hs = H_sum + (size_t)pair * F_ * D_;
  float* Hn = H_new + (size_t)pair * F_ * D_;
  #pragma unroll
  for (int i = 0; i < 4; i++) {
    size_t off = (size_t)(f0 + i) * D_ + dhalf * (D_ / 2) + d0;
    float4 hv = *(const float4*)&Hs[off];
    hv.x += acc[i][0]; hv.y += acc[i][1]; hv.z += acc[i][2]; hv.w += acc[i][3];
    *(float4*)&Hn[off] = hv;
  }
  if (dhalf == 0 && tid < F_)
    S_new[(size_t)pair * F_ + tid] = S_sum[(size_t)pair * F_ + tid] + sacc;
}

extern "C" void kernel_launch(void* const* d_in, const int* in_sizes, int n_in,
                              void* d_out, int out_size, void* d_ws, size_t ws_size,
                              hipStream_t stream) {
  const float* heap_score = (const float*)d_in[0];
  const float* K_top  = (const float*)d_in[1];
  const float* V_top  = (const float*)d_in[2];
  const float* FK_top = (const float*)d_in[3];
  const float* H_sum  = (const float*)d_in[4];
  const float* S_sum  = (const float*)d_in[5];
  const float* k_c    = (const float*)d_in[6];
  const float* v_c    = (const float*)d_in[7];
  const float* fk_c   = (const float*)d_in[8];
  const float* score_c = (const float*)d_in[9];

  float* out = (float*)d_out;
  float* heap_new = out;                                        // B*G*H
  float* K_new  = heap_new + (size_t)B_ * G_ * H_;              // B*G*H*D
  float* V_new  = K_new + (size_t)B_ * G_ * H_ * D_;
  float* FK_new = V_new + (size_t)B_ * G_ * H_ * D_;            // B*G*H*F
  float* H_new  = FK_new + (size_t)B_ * G_ * H_ * F_;           // B*H*F*D
  float* S_new  = H_new + (size_t)B_ * H_ * F_ * D_;            // B*H*F

  int* ws_idx = (int*)d_ws;                                     // 655360 B

  sort_kernel<<<B_ * H_, 512, 0, stream>>>(heap_score, score_c, heap_new, ws_idx);

  fused_kernel<<<ABLOCKS + NG, 256, 0, stream>>>(
      (const float4*)K_top, (const float4*)k_c,
      (const float4*)V_top, (const float4*)v_c,
      (const float4*)FK_top, (const float4*)fk_c,
      (float4*)K_new, (float4*)V_new, (float4*)FK_new,
      H_sum, S_sum, H_new, S_new, ws_idx);
}

// Round 8
// 100.618 us; speedup vs baseline: 2.0123x; 1.0695x over previous
//
#include <hip/hip_runtime.h>
#include <stdint.h>

#define B_ 2
#define C_ 512
#define G_ 2048
#define H_ 32
#define D_ 128
#define F_ 64
#define N_ (G_ + C_)      // 2560
#define NPAD 4096

// padded LDS slot for the sort's cross-wave exchanges
#define PIDX(i) ((i) + ((i) >> 4))

// native vector type for __builtin_nontemporal_* (HIP float4 is a class and
// is rejected by the builtin; this alias is layout-identical)
typedef float nt_f4 __attribute__((ext_vector_type(4)));

__device__ __forceinline__ unsigned long long shfl64_xor(unsigned long long x,
                                                         int lanex) {
  unsigned int lo = (unsigned int)x, hi = (unsigned int)(x >> 32);
  lo = __shfl_xor(lo, lanex, 64);
  hi = __shfl_xor(hi, lanex, 64);
  return ((unsigned long long)hi << 32) | (unsigned long long)lo;
}

// ---------------------------------------------------------------------------
// Kernel 1: per-(b,h) stable descending argsort of 2560 scores.
// Bitonic sort of 4096 uint64 keys, 512 threads x 8 register-resident elems.
// key = (~orderable(score) << 32) | index  (unique keys -> exact stable sort).
// Verified bit-exact (rounds 4/7: absmax 0.0).
// ---------------------------------------------------------------------------
__global__ __launch_bounds__(512) void sort_kernel(
    const float* __restrict__ heap_score,   // (B,G,H)
    const float* __restrict__ score_c,      // (B,C,H)
    float* __restrict__ heap_new,           // (B,G,H)
    int* __restrict__ ws_idx)               // (B*H, 2560)
{
  __shared__ unsigned long long keys[NPAD + (NPAD >> 4)];   // 34 KB
  const int blk = blockIdx.x;               // b*H + h
  const int b = blk >> 5, h = blk & 31;
  const int tid = threadIdx.x;

  unsigned long long v[8];
  #pragma unroll
  for (int l = 0; l < 8; ++l) {
    int r = tid * 8 + l;
    unsigned long long key = 0xFFFFFFFFFFFFFFFFull;   // dummy sinks to end
    if (r < N_) {
      float s = (r < G_) ? heap_score[((size_t)b * G_ + r) * H_ + h]
                         : score_c[((size_t)b * C_ + (r - G_)) * H_ + h];
      unsigned int bits = __float_as_uint(s);
      unsigned int ord = (bits & 0x80000000u) ? ~bits : (bits | 0x80000000u);
      key = ((unsigned long long)(~ord) << 32) | (unsigned int)r;
    }
    v[l] = key;
  }

  auto ce = [&](int x, int y, bool desc) {
    unsigned long long a = v[x], c = v[y];
    if ((a > c) != desc) { v[x] = c; v[y] = a; }
  };

  // ---- build sorted runs of 8 (stages k=2,4,8; i = 8*tid + l) ------------
  {
    const bool t1 = (tid & 1) != 0;         // (i & 8)
    ce(0,1,false); ce(2,3,true);  ce(4,5,false); ce(6,7,true);   // k=2
    ce(0,2,false); ce(1,3,false); ce(4,6,true);  ce(5,7,true);   // k=4 j=2
    ce(0,1,false); ce(2,3,false); ce(4,5,true);  ce(6,7,true);   // k=4 j=1
    ce(0,4,t1); ce(1,5,t1); ce(2,6,t1); ce(3,7,t1);              // k=8 j=4
    ce(0,2,t1); ce(1,3,t1); ce(4,6,t1); ce(5,7,t1);              // k=8 j=2
    ce(0,1,t1); ce(2,3,t1); ce(4,5,t1); ce(6,7,t1);              // k=8 j=1
  }

  // ---- stages k=16..4096 --------------------------------------------------
  for (int k = 16; k <= NPAD; k <<= 1) {
    const bool desc = (((unsigned)tid << 3) & (unsigned)k) != 0;  // (8t & k)

    for (int j = k >> 1; j >= 512; j >>= 1) {         // cross-wave: LDS
      __syncthreads();                                 // protect prior reads
      #pragma unroll
      for (int l = 0; l < 8; ++l) keys[PIDX(tid * 8 + l)] = v[l];
      __syncthreads();
      const int pt = tid ^ (j >> 3);
      const bool up = (tid & (j >> 3)) != 0;
      #pragma unroll
      for (int l = 0; l < 8; ++l) {
        unsigned long long o = keys[PIDX(pt * 8 + l)];
        unsigned long long mn = (v[l] < o) ? v[l] : o;
        unsigned long long mx = (v[l] < o) ? o : v[l];
        v[l] = (up != desc) ? mx : mn;
      }
    }

    #pragma unroll
    for (int j = 256; j >= 8; j >>= 1) {              // in-wave: shuffles
      if (j <= (k >> 1)) {
        const int lanex = j >> 3;                     // 1..32
        const bool up = (tid & lanex) != 0;
        #pragma unroll
        for (int l = 0; l < 8; ++l) {
          unsigned long long o = shfl64_xor(v[l], lanex);
          unsigned long long mn = (v[l] < o) ? v[l] : o;
          unsigned long long mx = (v[l] < o) ? o : v[l];
          v[l] = (up != desc) ? mx : mn;
        }
      }
    }

    ce(0,4,desc); ce(1,5,desc); ce(2,6,desc); ce(3,7,desc);      // j=4
    ce(0,2,desc); ce(1,3,desc); ce(4,6,desc); ce(5,7,desc);      // j=2
    ce(0,1,desc); ce(2,3,desc); ce(4,5,desc); ce(6,7,desc);      // j=1
  }

  // ---- outputs straight from registers -----------------------------------
  if (tid < N_ / 8) {                                  // tid < 320
    int4 lo4 = { (int)(unsigned)v[0], (int)(unsigned)v[1],
                 (int)(unsigned)v[2], (int)(unsigned)v[3] };
    int4 hi4 = { (int)(unsigned)v[4], (int)(unsigned)v[5],
                 (int)(unsigned)v[6], (int)(unsigned)v[7] };
    int4* p = (int4*)(ws_idx + (size_t)blk * N_);
    p[2 * tid] = lo4;
    p[2 * tid + 1] = hi4;
  }
  if (tid < G_ / 8) {                                  // tid < 256
    #pragma unroll
    for (int l = 0; l < 8; ++l) {
      int r = tid * 8 + l;
      unsigned int ord = ~(unsigned int)(v[l] >> 32);
      unsigned int bits = (ord & 0x80000000u) ? (ord & 0x7FFFFFFFu) : ~ord;
      heap_new[((size_t)b * G_ + r) * H_ + h] = __uint_as_float(bits);
    }
  }
}

// ---------------------------------------------------------------------------
// Kernel 2: fused gather + accumulation.
//  blocks [0, ABLOCKS): accum — 2 blocks per (b,h) (one per d-half), direct
//    H_new = H_sum + sum over 512 bottom rows (bit-exact vs np, round 7).
//  blocks [ABLOCKS, +NG): gather — ILP-8: 8 independent idx->data chains per
//    thread; all idx loads, then 8 NT loads (read-once, keep L2 clean), then
//    8 PLAIN stores (L2 write path — fills show 87% peak with plain stores).
// ---------------------------------------------------------------------------
#define NK4 ((long long)B_ * G_ * H_ * (D_ / 4))       // 4194304
#define NTOT4 ((long long)B_ * G_ * H_ * (2 * (D_ / 4) + (F_ / 4)))  // 10485760
#define EIGHTH (NTOT4 / 8)                             // 1310720 (mult of 256)
#define NG ((int)(EIGHTH / 256))                       // 5120 gather blocks
#define ABLOCKS (2 * B_ * H_)                          // 128 accum blocks
#define ACHUNK 16
#define AITER (C_ / ACHUNK)                            // 32

__device__ __forceinline__ void gather_one(
    long long gid,
    const float4* __restrict__ K_top,  const float4* __restrict__ k_c,
    const float4* __restrict__ V_top,  const float4* __restrict__ v_c,
    const float4* __restrict__ FK_top, const float4* __restrict__ fk_c,
    float4* __restrict__ K_new, float4* __restrict__ V_new,
    float4* __restrict__ FK_new,
    const int* __restrict__ ws_idx,
    const nt_f4** src, float4** dst)
{
  const float4 *top, *cc;
  float4* d;
  int lg;
  long long g2;
  if (gid < NK4)          { top = K_top;  cc = k_c;  d = K_new;  lg = 5; g2 = gid; }
  else if (gid < 2 * NK4) { top = V_top;  cc = v_c;  d = V_new;  lg = 5; g2 = gid - NK4; }
  else                    { top = FK_top; cc = fk_c; d = FK_new; lg = 4; g2 = gid - 2 * NK4; }

  int row = (int)(g2 >> lg);                // [0, B*G*H)
  int lane = (int)(g2 & ((1 << lg) - 1));
  int b = row >> 16;                        // G*H = 65536
  int g = (row >> 5) & (G_ - 1);
  int h = row & 31;
  int idx = ws_idx[((b << 5) | h) * N_ + g];
  const float4* s;
  if (idx < G_) s = top + (((size_t)(b * G_ + idx) * H_ + h) << lg) + lane;
  else          s = cc  + (((size_t)(b * C_ + (idx - G_)) * H_ + h) << lg) + lane;
  *src = (const nt_f4*)s;
  *dst = d + g2;
}

__global__ __launch_bounds__(256) void fused_kernel(
    const float4* __restrict__ K_top,  const float4* __restrict__ k_c,
    const float4* __restrict__ V_top,  const float4* __restrict__ v_c,
    const float4* __restrict__ FK_top, const float4* __restrict__ fk_c,
    float4* __restrict__ K_new, float4* __restrict__ V_new,
    float4* __restrict__ FK_new,
    const float* __restrict__ H_sum, const float* __restrict__ S_sum,
    float* __restrict__ H_new, float* __restrict__ S_new,
    const int* __restrict__ ws_idx)
{
  __shared__ float fk_s[ACHUNK][F_];        // 4 KB
  __shared__ float v_s[ACHUNK][D_ / 2];     // 4 KB
  __shared__ int idx_all[C_];               // 2 KB

  const int tid = threadIdx.x;

  if (blockIdx.x >= ABLOCKS) {
    // ----- gather: ILP-8, NT loads + plain stores -----------------------
    long long gid = (long long)(blockIdx.x - ABLOCKS) * 256 + tid;

    const nt_f4* s[8];
    float4* d[8];
    #pragma unroll
    for (int k = 0; k < 8; ++k)
      gather_one(gid + (long long)k * EIGHTH, K_top, k_c, V_top, v_c,
                 FK_top, fk_c, K_new, V_new, FK_new, ws_idx, &s[k], &d[k]);
    nt_f4 val[8];
    #pragma unroll
    for (int k = 0; k < 8; ++k) val[k] = __builtin_nontemporal_load(s[k]);
    #pragma unroll
    for (int k = 0; k < 8; ++k) *(nt_f4*)d[k] = val[k];
    return;
  }

  // ----- accum: one block per (b,h) x d-half ----------------------------
  const int pair = blockIdx.x >> 1;         // 0..63
  const int dhalf = blockIdx.x & 1;
  const int b = pair >> 5, h = pair & 31;

  for (int i = tid; i < C_; i += 256)
    idx_all[i] = ws_idx[pair * N_ + G_ + i];

  const int f0 = (tid >> 4) * 4;            // 0..60 (global f)
  const int d0 = (tid & 15) * 4;            // 0..60 (within half)
  float acc[4][4];
  #pragma unroll
  for (int i = 0; i < 4; i++)
    #pragma unroll
    for (int j = 0; j < 4; j++) acc[i][j] = 0.f;
  float sacc = 0.f;

  const int rr = tid >> 4, lane = tid & 15; // staging role: row, f4-slot

  for (int it = 0; it < AITER; ++it) {
    __syncthreads();                        // idx ready / prev compute done
    int idx = idx_all[it * ACHUNK + rr];
    {                                       // V half: 256 f4, 1 per thread
      const float4* src = (idx < G_)
          ? V_top + (((size_t)(b * G_ + idx) * H_ + h) << 5)
          : v_c  + (((size_t)(b * C_ + (idx - G_)) * H_ + h) << 5);
      ((float4*)v_s)[tid] = src[dhalf * 16 + lane];
    }
    {                                       // FK: 256 f4, 1 per thread
      const float4* src = (idx < G_)
          ? FK_top + (((size_t)(b * G_ + idx) * H_ + h) << 4)
          : fk_c  + (((size_t)(b * C_ + (idx - G_)) * H_ + h) << 4);
      ((float4*)fk_s)[tid] = src[lane];
    }
    __syncthreads();

    #pragma unroll 4
    for (int cc = 0; cc < ACHUNK; ++cc) {
      float4 fk4 = *(const float4*)&fk_s[cc][f0];
      float4 vv = *(const float4*)&v_s[cc][d0];
      float fs[4] = {fk4.x, fk4.y, fk4.z, fk4.w};
      float vs[4] = {vv.x, vv.y, vv.z, vv.w};
      #pragma unroll
      for (int i = 0; i < 4; i++)
        #pragma unroll
        for (int j = 0; j < 4; j++)
          acc[i][j] = fmaf(fs[i], vs[j], acc[i][j]);
    }
    if (dhalf == 0 && tid < F_) {
      float s = 0.f;
      #pragma unroll
      for (int cc = 0; cc < ACHUNK; ++cc) s += fk_s[cc][tid];
      sacc += s;
    }
  }

  // ----- epilogue: H_new = H_sum + acc, S_new = S_sum + sacc ------------
  const float* Hs = H_sum + (size_t)pair * F_ * D_;
  float* Hn = H_new + (size_t)pair * F_ * D_;
  #pragma unroll
  for (int i = 0; i < 4; i++) {
    size_t off = (size_t)(f0 + i) * D_ + dhalf * (D_ / 2) + d0;
    float4 hv = *(const float4*)&Hs[off];
    hv.x += acc[i][0]; hv.y += acc[i][1]; hv.z += acc[i][2]; hv.w += acc[i][3];
    *(float4*)&Hn[off] = hv;
  }
  if (dhalf == 0 && tid < F_)
    S_new[(size_t)pair * F_ + tid] = S_sum[(size_t)pair * F_ + tid] + sacc;
}

extern "C" void kernel_launch(void* const* d_in, const int* in_sizes, int n_in,
                              void* d_out, int out_size, void* d_ws, size_t ws_size,
                              hipStream_t stream) {
  const float* heap_score = (const float*)d_in[0];
  const float* K_top  = (const float*)d_in[1];
  const float* V_top  = (const float*)d_in[2];
  const float* FK_top = (const float*)d_in[3];
  const float* H_sum  = (const float*)d_in[4];
  const float* S_sum  = (const float*)d_in[5];
  const float* k_c    = (const float*)d_in[6];
  const float* v_c    = (const float*)d_in[7];
  const float* fk_c   = (const float*)d_in[8];
  const float* score_c = (const float*)d_in[9];

  float* out = (float*)d_out;
  float* heap_new = out;                                        // B*G*H
  float* K_new  = heap_new + (size_t)B_ * G_ * H_;              // B*G*H*D
  float* V_new  = K_new + (size_t)B_ * G_ * H_ * D_;
  float* FK_new = V_new + (size_t)B_ * G_ * H_ * D_;            // B*G*H*F
  float* H_new  = FK_new + (size_t)B_ * G_ * H_ * F_;           // B*H*F*D
  float* S_new  = H_new + (size_t)B_ * H_ * F_ * D_;            // B*H*F

  int* ws_idx = (int*)d_ws;                                     // 655360 B

  sort_kernel<<<B_ * H_, 512, 0, stream>>>(heap_score, score_c, heap_new, ws_idx);

  fused_kernel<<<ABLOCKS + NG, 256, 0, stream>>>(
      (const float4*)K_top, (const float4*)k_c,
      (const float4*)V_top, (const float4*)v_c,
      (const float4*)FK_top, (const float4*)fk_c,
      (float4*)K_new, (float4*)V_new, (float4*)FK_new,
      H_sum, S_sum, H_new, S_new, ws_idx);
}